// Round 7
// baseline (85.256 us; speedup 1.0000x reference)
//
#include <hip/hip_runtime.h>
#include <cstdint>

#define TPB 128   // one thread per row, 2 waves/block
#define LOG2E 1.4426950408889634f
#define LN2   0.69314718055994531f

__global__ __launch_bounds__(TPB, 2)
void pl_fused(const float* __restrict__ scores,
              const int* __restrict__ ranks,
              const int* __restrict__ mask,
              float* __restrict__ partials,
              unsigned* __restrict__ counter,
              float* __restrict__ out,
              int B, int nb)
{
    const int tid = threadIdx.x;
    const int row = blockIdx.x * TPB + tid;

    // thread t owns column t -> bank t%32 for every access, conflict-free,
    // no barrier needed (private column).
    __shared__ float eb[32 * TPB];   // 16 KB

    float per_row = 0.0f, cnt = 0.0f;

    if (row < B) {
        const float4* sp = reinterpret_cast<const float4*>(scores) + (size_t)row * 8;
        const int4*   rp = reinterpret_cast<const int4*>(ranks)  + (size_t)row * 8;
        const int4*   mp = reinterpret_cast<const int4*>(mask)   + (size_t)row * 8;

        // ---- per-chunk: build keys, count masked, write UNSHIFTED e to LDS.
        // key = mask*1024 + rank*32 + j (unique 11-bit stable-sort key;
        // key & 31 == original slot j; valid keys < 1024 sort to the front).
        // e = 2^(s*log2e), no max-shift: |s| <~ 5.5 keeps all downstream
        // products comfortably inside f32 range (verified numerically in R5).
        // Scores are consumed immediately -> no s[32] array is ever live.
        unsigned K[32];
        int nm = 0;
        #pragma unroll
        for (int c = 0; c < 8; ++c) {
            const float4 sv = sp[c];
            const int4   rv = rp[c];
            const int4   qv = mp[c];
            const int j = c * 4;
            K[j+0] = (unsigned)((qv.x << 10) + (rv.x << 5) + (j+0));
            K[j+1] = (unsigned)((qv.y << 10) + (rv.y << 5) + (j+1));
            K[j+2] = (unsigned)((qv.z << 10) + (rv.z << 5) + (j+2));
            K[j+3] = (unsigned)((qv.w << 10) + (rv.w << 5) + (j+3));
            nm += (qv.x + qv.y) + (qv.z + qv.w);
            eb[(j+0)*TPB + tid] = __builtin_amdgcn_exp2f(sv.x * LOG2E);
            eb[(j+1)*TPB + tid] = __builtin_amdgcn_exp2f(sv.y * LOG2E);
            eb[(j+2)*TPB + tid] = __builtin_amdgcn_exp2f(sv.z * LOG2E);
            eb[(j+3)*TPB + tid] = __builtin_amdgcn_exp2f(sv.w * LOG2E);
        }
        const int n = 32 - nm;

        // ---- key-only bitonic sort, ascending; 2 VALU per comparator
        #pragma unroll
        for (int kk = 2; kk <= 32; kk <<= 1) {
            #pragma unroll
            for (int jj = kk >> 1; jj > 0; jj >>= 1) {
                #pragma unroll
                for (int i = 0; i < 32; ++i) {
                    const int l = i ^ jj;
                    if (l > i) {
                        const unsigned a = K[i], b = K[l];
                        const unsigned mn = a < b ? a : b;
                        const unsigned mh = a < b ? b : a;
                        if ((i & kk) == 0) { K[i] = mn; K[l] = mh; }
                        else               { K[i] = mh; K[l] = mn; }
                    }
                }
            }
        }

        // ---- gather e in sorted order; K dies as addresses are consumed.
        // Validity below is p < n (masked entries sorted to the back), so
        // the gathered garbage for p >= n is never used.
        float es[32];
        #pragma unroll
        for (int p = 0; p < 32; ++p)
            es[p] = eb[(K[p] & 31u) * TPB + tid];

        // ---- suffix sums + grouped product logs:
        // loss = ln2 * sum_{p<n} (log2 T_p - log2 e_p), T_p = suffix sum.
        float t = 0.0f, lsum = 0.0f;
        #pragma unroll
        for (int g = 7; g >= 0; --g) {
            float pT = 1.0f, pE = 1.0f;
            #pragma unroll
            for (int q = 3; q >= 0; --q) {
                const int p = 4*g + q;
                const bool v = (p < n);
                t  += v ? es[p] : 0.0f;
                pT *= v ? t     : 1.0f;
                pE *= v ? es[p] : 1.0f;
            }
            lsum += __builtin_amdgcn_logf(pT) - __builtin_amdgcn_logf(pE);  // hw log2
        }

        if (n >= 2) {
            per_row = (LN2 * lsum) / (float)n;
            cnt = 1.0f;
        }
    }

    // ---- block reduction (2 waves)
    #pragma unroll
    for (int d = 32; d >= 1; d >>= 1) {
        per_row += __shfl_xor(per_row, d, 64);
        cnt     += __shfl_xor(cnt,     d, 64);
    }
    __shared__ float rbuf[4];
    __shared__ bool  amLast;
    if ((tid & 63) == 0) {
        rbuf[(tid >> 6)]     = per_row;
        rbuf[2 + (tid >> 6)] = cnt;
    }
    __syncthreads();
    if (tid == 0) {
        partials[2*blockIdx.x]     = rbuf[0] + rbuf[1];
        partials[2*blockIdx.x + 1] = rbuf[2] + rbuf[3];
        __threadfence();                          // publish partials, device scope
        const unsigned prev = atomicAdd(counter, 1u);
        amLast = (prev == (unsigned)(nb - 1));
    }
    __syncthreads();

    // ---- last block folds all partials (ascending order -> deterministic)
    if (amLast) {
        __threadfence();                          // acquire partials
        float sA = 0.0f, cA = 0.0f;
        for (int i = tid; i < nb; i += TPB) {
            const float2 v = reinterpret_cast<const float2*>(partials)[i];
            sA += v.x;
            cA += v.y;
        }
        #pragma unroll
        for (int d = 32; d >= 1; d >>= 1) {
            sA += __shfl_xor(sA, d, 64);
            cA += __shfl_xor(cA, d, 64);
        }
        __syncthreads();                          // rbuf reuse
        if ((tid & 63) == 0) {
            rbuf[(tid >> 6)]     = sA;
            rbuf[2 + (tid >> 6)] = cA;
        }
        __syncthreads();
        if (tid == 0) {
            const float S = rbuf[0] + rbuf[1];
            const float C = rbuf[2] + rbuf[3];
            out[0] = S / fmaxf(C, 1.0f);
        }
    }
}

extern "C" void kernel_launch(void* const* d_in, const int* in_sizes, int n_in,
                              void* d_out, int out_size, void* d_ws, size_t ws_size,
                              hipStream_t stream)
{
    const float* scores = (const float*)d_in[0];
    const int*   ranks  = (const int*)d_in[1];
    const int*   mask   = (const int*)d_in[2];

    const int B  = in_sizes[0] / 32;
    const int nb = (B + TPB - 1) / TPB;

    unsigned* counter  = (unsigned*)d_ws;                 // 4 B
    float*    partials = (float*)((char*)d_ws + 16);      // nb*2 floats

    hipMemsetAsync(counter, 0, 4, stream);                // graph-capturable
    pl_fused<<<nb, TPB, 0, stream>>>(scores, ranks, mask, partials, counter,
                                     (float*)d_out, B, nb);
}

// Round 9
// 28.455 us; speedup vs baseline: 2.9962x; 2.9962x over previous
//
#include <hip/hip_runtime.h>
#include <cstdint>

#define TPB 64    // one wave per block -> no barriers anywhere in pl_main
#define LOG2E 1.4426950408889634f
#define LN2   0.69314718055994531f

// Column byte-stride inside eb is TPB*4 bytes per slot j.
// key = mask*2^(JSH+10) + rank*2^(JSH+5) + j*2^JSH  (order-preserving prescale)
// so (key & JMASK) is directly the byte offset j*TPB*4 into a column.
#define JSH       8                      // log2(TPB*4) = log2(256)
#define RSH       (JSH + 5)              // rank field
#define MSH       (JSH + 10)             // mask field
#define JMASK     (31u << JSH)
#define VALID_LIM (1u << MSH)

static_assert(TPB * 4 == (1 << JSH), "JSH must equal log2(TPB*4)");

__global__ __launch_bounds__(TPB)
void pl_main(const float* __restrict__ scores,
             const int* __restrict__ ranks,
             const int* __restrict__ mask,
             float2* __restrict__ partials,
             int B)
{
    const int tid = threadIdx.x;
    const int row = blockIdx.x * TPB + tid;

    // thread t owns column t -> bank t%32 always, conflict-free, no barrier.
    __shared__ float eb[32 * TPB];   // 8 KB

    float per_row = 0.0f, cnt = 0.0f;

    if (row < B) {
        const float4* sp = reinterpret_cast<const float4*>(scores) + (size_t)row * 8;
        const int4*   rp = reinterpret_cast<const int4*>(ranks)  + (size_t)row * 8;
        const int4*   mp = reinterpret_cast<const int4*>(mask)   + (size_t)row * 8;

        float    s[32];
        unsigned K[32];

        #pragma unroll
        for (int c = 0; c < 8; ++c) {
            float4 sv = sp[c];
            int4   rv = rp[c];
            int4   qv = mp[c];
            const int j = c * 4;
            s[j+0] = sv.x; s[j+1] = sv.y; s[j+2] = sv.z; s[j+3] = sv.w;
            K[j+0] = (unsigned)((qv.x << MSH) + (rv.x << RSH) + ((j+0) << JSH));
            K[j+1] = (unsigned)((qv.y << MSH) + (rv.y << RSH) + ((j+1) << JSH));
            K[j+2] = (unsigned)((qv.z << MSH) + (rv.z << RSH) + ((j+2) << JSH));
            K[j+3] = (unsigned)((qv.w << MSH) + (rv.w << RSH) + ((j+3) << JSH));
        }

        // n valid, row max over valid, sum of valid scores
        int n = 0;
        float mx = -3.0e38f;
        float Ssum = 0.0f;
        #pragma unroll
        for (int j = 0; j < 32; ++j) {
            const bool v = (K[j] < VALID_LIM);
            n    += v ? 1 : 0;
            mx    = fmaxf(mx, v ? s[j] : -3.0e38f);
            Ssum += v ? s[j] : 0.0f;
        }
        const float xm = mx * LOG2E;

        // e_j = exp(s_j - mx), masked -> exactly 0; write to own LDS column
        #pragma unroll
        for (int j = 0; j < 32; ++j) {
            const bool v = (K[j] < VALID_LIM);
            float e = __builtin_amdgcn_exp2f(__builtin_fmaf(s[j], LOG2E, -xm));
            eb[j * TPB + tid] = v ? e : 0.0f;
        }

        // key-only bitonic sort, ascending; 2 VALU per comparator
        #pragma unroll
        for (int kk = 2; kk <= 32; kk <<= 1) {
            #pragma unroll
            for (int jj = kk >> 1; jj > 0; jj >>= 1) {
                #pragma unroll
                for (int i = 0; i < 32; ++i) {
                    const int l = i ^ jj;
                    if (l > i) {
                        const unsigned a = K[i], b = K[l];
                        const unsigned mn = a < b ? a : b;
                        const unsigned mh = a < b ? b : a;
                        if ((i & kk) == 0) { K[i] = mn; K[l] = mh; }
                        else               { K[i] = mh; K[l] = mn; }
                    }
                }
            }
        }

        // gather e in sorted order: byte offset is (K & JMASK) directly
        const char* col = reinterpret_cast<const char*>(eb + tid);
        float es[32];
        #pragma unroll
        for (int p = 0; p < 32; ++p)
            es[p] = *reinterpret_cast<const float*>(col + (K[p] & JMASK));

        // suffix sums + grouped product logs (range-safe 4-wide groups)
        float t = 0.0f, lsum = 0.0f;
        #pragma unroll
        for (int g = 7; g >= 0; --g) {
            float prod = 1.0f;
            #pragma unroll
            for (int q = 3; q >= 0; --q) {
                const int p = 4*g + q;
                t    += es[p];
                prod *= (K[p] < VALID_LIM) ? t : 1.0f;
            }
            lsum += __builtin_amdgcn_logf(prod);   // hw log2
        }

        if (n >= 2) {
            const float loss = (float)n * mx + LN2 * lsum - Ssum;
            per_row = loss / (float)n;
            cnt = 1.0f;
        }
    }

    // single-wave reduction; lane 0 stores the block partial
    #pragma unroll
    for (int d = 32; d >= 1; d >>= 1) {
        per_row += __shfl_xor(per_row, d, 64);
        cnt     += __shfl_xor(cnt,     d, 64);
    }
    if (tid == 0)
        partials[blockIdx.x] = make_float2(per_row, cnt);
}

__global__ __launch_bounds__(256)
void pl_final(const float2* __restrict__ partials, int nb, float* __restrict__ out)
{
    const int tid = threadIdx.x;
    float s = 0.0f, c = 0.0f;
    for (int i = tid; i < nb; i += 256) {
        const float2 v = partials[i];
        s += v.x;
        c += v.y;
    }
    #pragma unroll
    for (int d = 32; d >= 1; d >>= 1) {
        s += __shfl_xor(s, d, 64);
        c += __shfl_xor(c, d, 64);
    }
    __shared__ float sb[8];
    if ((tid & 63) == 0) {
        sb[tid >> 6]       = s;
        sb[4 + (tid >> 6)] = c;
    }
    __syncthreads();
    if (tid == 0) {
        const float S = (sb[0] + sb[1]) + (sb[2] + sb[3]);
        const float C = (sb[4] + sb[5]) + (sb[6] + sb[7]);
        out[0] = S / fmaxf(C, 1.0f);
    }
}

extern "C" void kernel_launch(void* const* d_in, const int* in_sizes, int n_in,
                              void* d_out, int out_size, void* d_ws, size_t ws_size,
                              hipStream_t stream)
{
    const float* scores = (const float*)d_in[0];
    const int*   ranks  = (const int*)d_in[1];
    const int*   mask   = (const int*)d_in[2];

    const int B  = in_sizes[0] / 32;
    const int nb = (B + TPB - 1) / TPB;

    float2* partials = (float2*)d_ws;   // nb float2

    pl_main<<<nb, TPB, 0, stream>>>(scores, ranks, mask, partials, B);
    pl_final<<<1, 256, 0, stream>>>(partials, nb, (float*)d_out);
}